// Round 3
// baseline (121.268 us; speedup 1.0000x reference)
//
#include <hip/hip_runtime.h>
#include <hip/hip_bf16.h>

// Problem: N=8, L=S=1024, C=256, H=8, D=32
// out = (v1 * softmax_S(q k^T / sqrt(D)) v2) @ Wp^T + bp
// Pipeline: prep (add+bf16) -> 4 projections (MFMA GEMM) -> fused attn -> out GEMM

typedef __bf16 bf16_t;
using bf16x8 = __attribute__((ext_vector_type(8))) __bf16;
using f32x4  = __attribute__((ext_vector_type(4))) float;

#define NB 8
#define LL 1024
#define SS 1024
#define CC 256
#define HH 8
#define DD 32
#define MTOK (NB * LL)   // 8192 tokens for both L-side and S-side

// 1/sqrt(D) * log2(e): softmax done in exp2 space, folded into Q at proj time
#define QSCALE (0.17677669529663688f * 1.4426950408889634f)

static __device__ __forceinline__ f32x4 mfma16(bf16x8 a, bf16x8 b, f32x4 c) {
  return __builtin_amdgcn_mfma_f32_16x16x32_bf16(a, b, c, 0, 0, 0);
}
static __device__ __forceinline__ float fexp2(float x) {
  return __builtin_amdgcn_exp2f(x);
}

// ---------------------------------------------------------------------------
// Kernel 1: xq = bf16(x + xe), sk = bf16(s1 + se), plus bf16 copies of weights
// ---------------------------------------------------------------------------
__global__ __launch_bounds__(256) void prep_kernel(
    const float* __restrict__ x, const float* __restrict__ xe,
    const float* __restrict__ s1, const float* __restrict__ se,
    const float* __restrict__ wq, const float* __restrict__ wk,
    const float* __restrict__ wv, const float* __restrict__ wp,
    bf16_t* __restrict__ XQ, bf16_t* __restrict__ SK, bf16_t* __restrict__ Wall) {
  const int TOK4 = (MTOK * CC) / 4;  // 524288 float4 per token tensor
  const int W4   = (CC * CC) / 4;    // 16384 float4 per weight matrix
  int i = blockIdx.x * 256 + threadIdx.x;
  const int stride = gridDim.x * 256;
  const int total = 2 * TOK4 + 4 * W4;
  for (; i < total; i += stride) {
    const float4* pa;
    const float4* pb = nullptr;
    bf16_t* o;
    int j;
    if (i < TOK4) {
      pa = (const float4*)x; pb = (const float4*)xe; o = XQ; j = i;
    } else if (i < 2 * TOK4) {
      pa = (const float4*)s1; pb = (const float4*)se; o = SK; j = i - TOK4;
    } else {
      int wi = i - 2 * TOK4;
      int w = wi >> 14;          // / W4
      j = wi & (W4 - 1);
      pa = (const float4*)(w == 0 ? wq : w == 1 ? wk : w == 2 ? wv : wp);
      o = Wall + (size_t)w * CC * CC;
    }
    float4 va = pa[j];
    if (pb) {
      float4 vb = pb[j];
      va.x += vb.x; va.y += vb.y; va.z += vb.z; va.w += vb.w;
    }
    bf16_t t4[4] __attribute__((aligned(8))) = {
        (bf16_t)va.x, (bf16_t)va.y, (bf16_t)va.z, (bf16_t)va.w};
    *(uint2*)(o + 4 * (size_t)j) = *(const uint2*)t4;
  }
}

// ---------------------------------------------------------------------------
// Kernel 2: projections (NT GEMM).  z=0: Q (pre-scaled by QSCALE), z=1: K,
// z=2: V1, z=3: V2T stored transposed per head [n][h][d][s].
// ---------------------------------------------------------------------------
__global__ __launch_bounds__(256) void proj_kernel(
    const bf16_t* __restrict__ XQ, const bf16_t* __restrict__ SK,
    const bf16_t* __restrict__ Wall,
    bf16_t* __restrict__ Qw, bf16_t* __restrict__ Kw,
    bf16_t* __restrict__ V1w, bf16_t* __restrict__ V2T) {
  const int lane = threadIdx.x & 63;
  const int wid = threadIdx.x >> 6;
  const int wm = wid >> 1, wn = wid & 1;
  const int r = lane & 15, g = lane >> 4;
  const int bm = blockIdx.x * 64, bn = blockIdx.y * 64;
  const int z = blockIdx.z;

  const bf16_t* A = (z == 1 || z == 3) ? SK : XQ;
  const bf16_t* W = Wall + (size_t)(z == 0 ? 0 : z == 1 ? 1 : 2) * CC * CC;

  const int row_a0 = bm + wm * 32;
  const int col_b0 = bn + wn * 32;

  f32x4 acc[2][2] = {};
#pragma unroll
  for (int k0 = 0; k0 < CC; k0 += 32) {
    bf16x8 a0 = *(const bf16x8*)(A + (size_t)(row_a0 + r) * CC + k0 + g * 8);
    bf16x8 a1 = *(const bf16x8*)(A + (size_t)(row_a0 + 16 + r) * CC + k0 + g * 8);
    bf16x8 b0 = *(const bf16x8*)(W + (size_t)(col_b0 + r) * CC + k0 + g * 8);
    bf16x8 b1 = *(const bf16x8*)(W + (size_t)(col_b0 + 16 + r) * CC + k0 + g * 8);
    acc[0][0] = mfma16(a0, b0, acc[0][0]);
    acc[0][1] = mfma16(a0, b1, acc[0][1]);
    acc[1][0] = mfma16(a1, b0, acc[1][0]);
    acc[1][1] = mfma16(a1, b1, acc[1][1]);
  }

  const float sc = (z == 0) ? QSCALE : 1.f;
  bf16_t* O = (z == 0) ? Qw : (z == 1) ? Kw : V1w;
#pragma unroll
  for (int i = 0; i < 2; ++i) {
#pragma unroll
    for (int j = 0; j < 2; ++j) {
      const int row_base = row_a0 + i * 16 + g * 4;
      const int col = col_b0 + j * 16 + r;
      if (z < 3) {
#pragma unroll
        for (int t = 0; t < 4; ++t)
          O[(size_t)(row_base + t) * CC + col] = (bf16_t)(acc[i][j][t] * sc);
      } else {
        // transposed per-head store: V2T[((n*H + h)*D + d)][s]
        const int n = row_base >> 10;
        const int s = row_base & (SS - 1);
        const int h = col >> 5;
        const int d = col & (DD - 1);
        bf16_t t4[4] __attribute__((aligned(8)));
#pragma unroll
        for (int t = 0; t < 4; ++t) t4[t] = (bf16_t)acc[i][j][t];
        *(uint2*)(V2T + ((size_t)((n * HH + h) * DD + d)) * SS + s) =
            *(const uint2*)t4;
      }
    }
  }
}

// ---------------------------------------------------------------------------
// Kernel 3: fused flash attention + v1 gating — SINGLE-PASS softmax.
// Grid (L/16, H, N) = 4096 blocks, 4 waves/WG. Each wave: same 16 L-rows,
// disjoint 256-S strip, entire P^T strip held in registers (16 x f32x4).
// Phase 1: 16 back-to-back QK^T MFMAs (swapped: rows=S, col(lane&15)=L).
// Phase 2: ONE exact softmax pass (1 fmax tree + 2 shfl + exp2 + 2 shfl).
// Phase 3: stage P^T bf16 in LDS, 16 back-to-back PV MFMAs (O^T: rows=D).
// Merge across the 4 S-strips via LDS (oslot aliases dead p_lds).
// ---------------------------------------------------------------------------
__global__ __launch_bounds__(256) void attn_kernel(
    const bf16_t* __restrict__ Qw, const bf16_t* __restrict__ Kw,
    const bf16_t* __restrict__ V1w, const bf16_t* __restrict__ V2T,
    bf16_t* __restrict__ MSG) {
  __shared__ __align__(16) bf16_t p_lds[4][16][264];  // [wave][l][s+8pad] 33.8KB
  __shared__ float ml[4][2][16];                      // per-wave m,l per L-col
  float (*oslot)[16][40] = (float (*)[16][40]) & p_lds[0][0][0];  // aliased

  const int lane = threadIdx.x & 63;
  const int wid = threadIdx.x >> 6;
  const int r = lane & 15, g = lane >> 4;
  const int h = blockIdx.y;
  const int n = blockIdx.z;
  const int l0 = blockIdx.x * 16;
  const size_t tokQ = (size_t)n * LL + l0;

  // Q fragment (B-operand of swapped QK^T); Q is pre-scaled by QSCALE
  const bf16x8 qf = *(const bf16x8*)(Qw + (tokQ + r) * CC + h * DD + g * 8);
  const bf16_t* Kb = Kw + ((size_t)n * SS) * CC + h * DD;
  const bf16_t* Vt = V2T + ((size_t)(n * HH + h)) * DD * SS;
  const int sbase = wid * 256;

  const f32x4 zero = {0.f, 0.f, 0.f, 0.f};

  // ---- Phase 1: all 16 QK^T MFMAs (independent)
  f32x4 pt[16];
#pragma unroll
  for (int c = 0; c < 16; ++c) {
    bf16x8 kf =
        *(const bf16x8*)(Kb + (size_t)(sbase + c * 16 + r) * CC + g * 8);
    pt[c] = mfma16(kf, qf, zero);  // rows s = sbase + 16c + 4g + i, col l = r
  }

  // ---- Phase 2: single exact softmax over the strip
  float mx = fmaxf(fmaxf(pt[0][0], pt[0][1]), fmaxf(pt[0][2], pt[0][3]));
#pragma unroll
  for (int c = 1; c < 16; ++c)
    mx = fmaxf(mx, fmaxf(fmaxf(pt[c][0], pt[c][1]), fmaxf(pt[c][2], pt[c][3])));
  mx = fmaxf(mx, __shfl_xor(mx, 16));
  mx = fmaxf(mx, __shfl_xor(mx, 32));

  float ps0 = 0.f, ps1 = 0.f, ps2 = 0.f, ps3 = 0.f;
#pragma unroll
  for (int c = 0; c < 16; ++c) {
    float p0 = fexp2(pt[c][0] - mx);
    float p1 = fexp2(pt[c][1] - mx);
    float p2 = fexp2(pt[c][2] - mx);
    float p3 = fexp2(pt[c][3] - mx);
    ps0 += p0; ps1 += p1; ps2 += p2; ps3 += p3;
    bf16_t pb[4] __attribute__((aligned(8))) = {(bf16_t)p0, (bf16_t)p1,
                                                (bf16_t)p2, (bf16_t)p3};
    *(uint2*)&p_lds[wid][r][c * 16 + g * 4] = *(const uint2*)pb;
  }
  float psum = (ps0 + ps1) + (ps2 + ps3);
  psum += __shfl_xor(psum, 16);
  psum += __shfl_xor(psum, 32);
  if (lane < 16) {
    ml[wid][0][lane] = mx;
    ml[wid][1][lane] = psum;
  }

  // ---- Phase 3: all 16 PV MFMAs.  O^T[d][l] += V2T[d][s] * P^T[s][l]
  f32x4 o0 = zero, o1 = zero;  // rows d = g*4+i / 16+g*4+i, col l = r
#pragma unroll
  for (int u = 0; u < 8; ++u) {
    bf16x8 pf = *(const bf16x8*)&p_lds[wid][r][u * 32 + g * 8];
    bf16x8 va = *(const bf16x8*)(Vt + (size_t)r * SS + sbase + u * 32 + g * 8);
    bf16x8 vb =
        *(const bf16x8*)(Vt + (size_t)(16 + r) * SS + sbase + u * 32 + g * 8);
    o0 = mfma16(va, pf, o0);
    o1 = mfma16(vb, pf, o1);
  }

  // ---- merge across the 4 S-strip waves (oslot aliases p_lds; barrier first)
  __syncthreads();  // all waves done reading their p_lds
  *(f32x4*)&oslot[wid][r][g * 4] = o0;
  *(f32x4*)&oslot[wid][r][16 + g * 4] = o1;
  __syncthreads();

  if (wid == 0) {
    const float m0 = ml[0][0][r], m1 = ml[1][0][r];
    const float m2 = ml[2][0][r], m3 = ml[3][0][r];
    const float M = fmaxf(fmaxf(m0, m1), fmaxf(m2, m3));
    const float f0 = fexp2(m0 - M), f1 = fexp2(m1 - M);
    const float f2 = fexp2(m2 - M), f3 = fexp2(m3 - M);
    const float lsum = f0 * ml[0][1][r] + f1 * ml[1][1][r] +
                       f2 * ml[2][1][r] + f3 * ml[3][1][r];
    const float linv = 1.f / lsum;

    f32x4 a0 = zero, a1 = zero;
    const float fw[4] = {f0, f1, f2, f3};
#pragma unroll
    for (int w = 0; w < 4; ++w) {
      f32x4 s0v = *(const f32x4*)&oslot[w][r][g * 4];
      f32x4 s1v = *(const f32x4*)&oslot[w][r][16 + g * 4];
#pragma unroll
      for (int i = 0; i < 4; ++i) {
        a0[i] += fw[w] * s0v[i];
        a1[i] += fw[w] * s1v[i];
      }
    }

    // V1 gate + store: lane owns l = r, d = {g*4+i} and {16+g*4+i}
    const bf16_t* V1b = V1w + (tokQ + r) * CC + h * DD;
    bf16_t* Mb = MSG + (tokQ + r) * CC + h * DD;
    uint2 v1u0 = *(const uint2*)(V1b + g * 4);
    uint2 v1u1 = *(const uint2*)(V1b + 16 + g * 4);
    const bf16_t* v1a = (const bf16_t*)&v1u0;
    const bf16_t* v1b = (const bf16_t*)&v1u1;
    bf16_t ob0[4] __attribute__((aligned(8)));
    bf16_t ob1[4] __attribute__((aligned(8)));
#pragma unroll
    for (int i = 0; i < 4; ++i) {
      ob0[i] = (bf16_t)(a0[i] * linv * (float)v1a[i]);
      ob1[i] = (bf16_t)(a1[i] * linv * (float)v1b[i]);
    }
    *(uint2*)(Mb + g * 4) = *(const uint2*)ob0;
    *(uint2*)(Mb + 16 + g * 4) = *(const uint2*)ob1;
  }
}

// ---------------------------------------------------------------------------
// Kernel 4: out = MSG @ Wp^T + bp   (f32 output)
// ---------------------------------------------------------------------------
__global__ __launch_bounds__(256) void out_kernel(
    const bf16_t* __restrict__ MSG, const bf16_t* __restrict__ Wp,
    const float* __restrict__ bp, float* __restrict__ out) {
  const int lane = threadIdx.x & 63;
  const int wid = threadIdx.x >> 6;
  const int wm = wid >> 1, wn = wid & 1;
  const int r = lane & 15, g = lane >> 4;
  const int bm = blockIdx.x * 64, bn = blockIdx.y * 64;
  const int row_a0 = bm + wm * 32;
  const int col_b0 = bn + wn * 32;

  f32x4 acc[2][2] = {};
#pragma unroll
  for (int k0 = 0; k0 < CC; k0 += 32) {
    bf16x8 a0 = *(const bf16x8*)(MSG + (size_t)(row_a0 + r) * CC + k0 + g * 8);
    bf16x8 a1 = *(const bf16x8*)(MSG + (size_t)(row_a0 + 16 + r) * CC + k0 + g * 8);
    bf16x8 b0 = *(const bf16x8*)(Wp + (size_t)(col_b0 + r) * CC + k0 + g * 8);
    bf16x8 b1 = *(const bf16x8*)(Wp + (size_t)(col_b0 + 16 + r) * CC + k0 + g * 8);
    acc[0][0] = mfma16(a0, b0, acc[0][0]);
    acc[0][1] = mfma16(a0, b1, acc[0][1]);
    acc[1][0] = mfma16(a1, b0, acc[1][0]);
    acc[1][1] = mfma16(a1, b1, acc[1][1]);
  }
#pragma unroll
  for (int i = 0; i < 2; ++i) {
#pragma unroll
    for (int j = 0; j < 2; ++j) {
      const int row_base = row_a0 + i * 16 + g * 4;
      const int col = col_b0 + j * 16 + r;
      const float bv = bp[col];
#pragma unroll
      for (int t = 0; t < 4; ++t)
        out[(size_t)(row_base + t) * CC + col] = acc[i][j][t] + bv;
    }
  }
}

// ---------------------------------------------------------------------------
extern "C" void kernel_launch(void* const* d_in, const int* in_sizes, int n_in,
                              void* d_out, int out_size, void* d_ws,
                              size_t ws_size, hipStream_t stream) {
  const float* x  = (const float*)d_in[0];
  const float* s1 = (const float*)d_in[1];
  const float* xe = (const float*)d_in[2];
  const float* se = (const float*)d_in[3];
  const float* Wq = (const float*)d_in[4];
  const float* Wk = (const float*)d_in[5];
  const float* Wv = (const float*)d_in[6];
  const float* Wp = (const float*)d_in[7];
  const float* bp = (const float*)d_in[8];
  float* out = (float*)d_out;

  char* ws = (char*)d_ws;
  bf16_t* XQ   = (bf16_t*)(ws);                     // 4 MB  [8192][256]
  bf16_t* SK   = (bf16_t*)(ws + (4u << 20));        // 4 MB
  bf16_t* Wall = (bf16_t*)(ws + (8u << 20));        // 512 KB: Wq,Wk,Wv,Wp bf16
  bf16_t* Qw   = (bf16_t*)(ws + (9u << 20));        // 4 MB (pre-scaled)
  bf16_t* Kw   = (bf16_t*)(ws + (13u << 20));       // 4 MB
  bf16_t* V1w  = (bf16_t*)(ws + (17u << 20));       // 4 MB
  bf16_t* V2T  = (bf16_t*)(ws + (21u << 20));       // 4 MB [n][h][d][s]
  bf16_t* MSG  = (bf16_t*)(ws + (25u << 20));       // 4 MB
  bf16_t* Wpb  = Wall + 3 * CC * CC;

  prep_kernel<<<2048, 256, 0, stream>>>(x, xe, s1, se, Wq, Wk, Wv, Wp, XQ, SK,
                                        Wall);
  proj_kernel<<<dim3(MTOK / 64, CC / 64, 4), 256, 0, stream>>>(
      XQ, SK, Wall, Qw, Kw, V1w, V2T);
  attn_kernel<<<dim3(LL / 16, HH, NB), 256, 0, stream>>>(Qw, Kw, V1w, V2T, MSG);
  out_kernel<<<dim3(MTOK / 64, CC / 64, 1), 256, 0, stream>>>(MSG, Wpb, bp, out);
}

// Round 4
// 82.746 us; speedup vs baseline: 1.4655x; 1.4655x over previous
//
#include <hip/hip_runtime.h>
#include <hip/hip_bf16.h>

// Problem: N=8, L=S=1024, C=256, H=8, D=32
// out = (v1 * softmax_S(q k^T / sqrt(D)) v2) @ Wp^T + bp
// Pipeline: prep (add+bf16) -> 4 projections (MFMA GEMM) -> fused attn -> out GEMM

typedef __bf16 bf16_t;
using bf16x8 = __attribute__((ext_vector_type(8))) __bf16;
using f32x4  = __attribute__((ext_vector_type(4))) float;

#define NB 8
#define LL 1024
#define SS 1024
#define CC 256
#define HH 8
#define DD 32
#define MTOK (NB * LL)   // 8192 tokens for both L-side and S-side

// 1/sqrt(D) * log2(e): softmax done in exp2 space, folded into Q at proj time
#define QSCALE (0.17677669529663688f * 1.4426950408889634f)

static __device__ __forceinline__ f32x4 mfma16(bf16x8 a, bf16x8 b, f32x4 c) {
  return __builtin_amdgcn_mfma_f32_16x16x32_bf16(a, b, c, 0, 0, 0);
}
static __device__ __forceinline__ float fexp2(float x) {
  return __builtin_amdgcn_exp2f(x);
}

// ---------------------------------------------------------------------------
// Kernel 1: xq = bf16(x + xe), sk = bf16(s1 + se), plus bf16 copies of weights
// ---------------------------------------------------------------------------
__global__ __launch_bounds__(256) void prep_kernel(
    const float* __restrict__ x, const float* __restrict__ xe,
    const float* __restrict__ s1, const float* __restrict__ se,
    const float* __restrict__ wq, const float* __restrict__ wk,
    const float* __restrict__ wv, const float* __restrict__ wp,
    bf16_t* __restrict__ XQ, bf16_t* __restrict__ SK, bf16_t* __restrict__ Wall) {
  const int TOK4 = (MTOK * CC) / 4;  // 524288 float4 per token tensor
  const int W4   = (CC * CC) / 4;    // 16384 float4 per weight matrix
  int i = blockIdx.x * 256 + threadIdx.x;
  const int stride = gridDim.x * 256;
  const int total = 2 * TOK4 + 4 * W4;
  for (; i < total; i += stride) {
    const float4* pa;
    const float4* pb = nullptr;
    bf16_t* o;
    int j;
    if (i < TOK4) {
      pa = (const float4*)x; pb = (const float4*)xe; o = XQ; j = i;
    } else if (i < 2 * TOK4) {
      pa = (const float4*)s1; pb = (const float4*)se; o = SK; j = i - TOK4;
    } else {
      int wi = i - 2 * TOK4;
      int w = wi >> 14;          // / W4
      j = wi & (W4 - 1);
      pa = (const float4*)(w == 0 ? wq : w == 1 ? wk : w == 2 ? wv : wp);
      o = Wall + (size_t)w * CC * CC;
    }
    float4 va = pa[j];
    if (pb) {
      float4 vb = pb[j];
      va.x += vb.x; va.y += vb.y; va.z += vb.z; va.w += vb.w;
    }
    bf16_t t4[4] __attribute__((aligned(8))) = {
        (bf16_t)va.x, (bf16_t)va.y, (bf16_t)va.z, (bf16_t)va.w};
    *(uint2*)(o + 4 * (size_t)j) = *(const uint2*)t4;
  }
}

// ---------------------------------------------------------------------------
// Kernel 2: projections (NT GEMM).  z=0: Q (pre-scaled by QSCALE), z=1: K,
// z=2: V1, z=3: V2T stored transposed per head [n][h][d][s].
// ---------------------------------------------------------------------------
__global__ __launch_bounds__(256) void proj_kernel(
    const bf16_t* __restrict__ XQ, const bf16_t* __restrict__ SK,
    const bf16_t* __restrict__ Wall,
    bf16_t* __restrict__ Qw, bf16_t* __restrict__ Kw,
    bf16_t* __restrict__ V1w, bf16_t* __restrict__ V2T) {
  const int lane = threadIdx.x & 63;
  const int wid = threadIdx.x >> 6;
  const int wm = wid >> 1, wn = wid & 1;
  const int r = lane & 15, g = lane >> 4;
  const int bm = blockIdx.x * 64, bn = blockIdx.y * 64;
  const int z = blockIdx.z;

  const bf16_t* A = (z == 1 || z == 3) ? SK : XQ;
  const bf16_t* W = Wall + (size_t)(z == 0 ? 0 : z == 1 ? 1 : 2) * CC * CC;

  const int row_a0 = bm + wm * 32;
  const int col_b0 = bn + wn * 32;

  f32x4 acc[2][2] = {};
#pragma unroll
  for (int k0 = 0; k0 < CC; k0 += 32) {
    bf16x8 a0 = *(const bf16x8*)(A + (size_t)(row_a0 + r) * CC + k0 + g * 8);
    bf16x8 a1 = *(const bf16x8*)(A + (size_t)(row_a0 + 16 + r) * CC + k0 + g * 8);
    bf16x8 b0 = *(const bf16x8*)(W + (size_t)(col_b0 + r) * CC + k0 + g * 8);
    bf16x8 b1 = *(const bf16x8*)(W + (size_t)(col_b0 + 16 + r) * CC + k0 + g * 8);
    acc[0][0] = mfma16(a0, b0, acc[0][0]);
    acc[0][1] = mfma16(a0, b1, acc[0][1]);
    acc[1][0] = mfma16(a1, b0, acc[1][0]);
    acc[1][1] = mfma16(a1, b1, acc[1][1]);
  }

  const float sc = (z == 0) ? QSCALE : 1.f;
  bf16_t* O = (z == 0) ? Qw : (z == 1) ? Kw : V1w;
#pragma unroll
  for (int i = 0; i < 2; ++i) {
#pragma unroll
    for (int j = 0; j < 2; ++j) {
      const int row_base = row_a0 + i * 16 + g * 4;
      const int col = col_b0 + j * 16 + r;
      if (z < 3) {
#pragma unroll
        for (int t = 0; t < 4; ++t)
          O[(size_t)(row_base + t) * CC + col] = (bf16_t)(acc[i][j][t] * sc);
      } else {
        // transposed per-head store: V2T[((n*H + h)*D + d)][s]
        const int n = row_base >> 10;
        const int s = row_base & (SS - 1);
        const int h = col >> 5;
        const int d = col & (DD - 1);
        bf16_t t4[4] __attribute__((aligned(8)));
#pragma unroll
        for (int t = 0; t < 4; ++t) t4[t] = (bf16_t)acc[i][j][t];
        *(uint2*)(V2T + ((size_t)((n * HH + h) * DD + d)) * SS + s) =
            *(const uint2*)t4;
      }
    }
  }
}

// ---------------------------------------------------------------------------
// Kernel 3: fused flash attention + v1 gating — LDS-staged K/V, L-tile 64.
// Grid (L/64, H, N) = 1024 blocks, 4 waves/WG, wave w owns L-rows l0+16w..+16.
// Per S-chunk (128): block cooperatively stages K-chunk [128][32] and
// V2T-chunk [32][128] in LDS (once per BLOCK, 4x less global traffic than
// per-wave reads with 16-L blocks); every wave computes QK^T (8 MFMA),
// online softmax (lane-local rescale: O^T layout), PV (8 MFMA) from LDS.
// ---------------------------------------------------------------------------
__global__ __launch_bounds__(256) void attn_kernel(
    const bf16_t* __restrict__ Qw, const bf16_t* __restrict__ Kw,
    const bf16_t* __restrict__ V1w, const bf16_t* __restrict__ V2T,
    bf16_t* __restrict__ MSG) {
  __shared__ __align__(16) bf16_t k_lds[128][40];      // [s][d+8pad]  10.0 KB
  __shared__ __align__(16) bf16_t v_lds[32][136];      // [d][s+8pad]   8.5 KB
  __shared__ __align__(16) bf16_t p_lds[4][16][136];   // [w][l][s+8]  17.0 KB

  const int lane = threadIdx.x & 63;
  const int wid = threadIdx.x >> 6;
  const int t = threadIdx.x;
  const int r = lane & 15, g = lane >> 4;
  const int h = blockIdx.y;
  const int n = blockIdx.z;
  const int l0 = blockIdx.x * 64;
  const size_t tokQ = (size_t)n * LL + l0 + wid * 16;  // wave's 16 L-rows

  // Q fragment (B-operand of swapped QK^T); Q is pre-scaled by QSCALE
  const bf16x8 qf = *(const bf16x8*)(Qw + (tokQ + r) * CC + h * DD + g * 8);
  const bf16_t* Kb = Kw + ((size_t)n * SS) * CC + h * DD;
  const bf16_t* Vt = V2T + ((size_t)(n * HH + h)) * DD * SS;

  // staging indices (whole block)
  const int ksr = t >> 2, kq = t & 3;   // K: rows 0..63 (+64), d-quad 0..3
  const int vdr = t >> 3, vq = t & 7;   // V: d-row 0..31, s-quad 0..7 (+8)

  float m_run = -1e30f;
  float l_run = 0.f;
  f32x4 o0 = {0.f, 0.f, 0.f, 0.f};  // O^T rows d = g*4+i,    col l = r
  f32x4 o1 = {0.f, 0.f, 0.f, 0.f};  // O^T rows d = 16+g*4+i, col l = r
  const f32x4 zero = {0.f, 0.f, 0.f, 0.f};

  for (int c = 0; c < 8; ++c) {
    const int s0 = c * 128;
    // ---- cooperative stage K (8 KB) + V (8 KB) into LDS
    {
      uint4 ka = *(const uint4*)(Kb + (size_t)(s0 + ksr) * CC + kq * 8);
      uint4 kb2 = *(const uint4*)(Kb + (size_t)(s0 + 64 + ksr) * CC + kq * 8);
      uint4 va = *(const uint4*)(Vt + (size_t)vdr * SS + s0 + vq * 8);
      uint4 vb = *(const uint4*)(Vt + (size_t)vdr * SS + s0 + 64 + vq * 8);
      *(uint4*)&k_lds[ksr][kq * 8] = ka;
      *(uint4*)&k_lds[64 + ksr][kq * 8] = kb2;
      *(uint4*)&v_lds[vdr][vq * 8] = va;
      *(uint4*)&v_lds[vdr][64 + vq * 8] = vb;
    }
    __syncthreads();

    // ---- QK^T: 8 MFMAs from LDS (rows = S, col(lane&15) = L)
    f32x4 pt[8];
#pragma unroll
    for (int m = 0; m < 8; ++m) {
      bf16x8 kf = *(const bf16x8*)&k_lds[m * 16 + r][g * 8];
      pt[m] = mfma16(kf, qf, zero);  // s = s0 + 16m + 4g + i
    }

    // ---- online softmax (stats per l-column, lane-local after shfl)
    float mx = fmaxf(fmaxf(pt[0][0], pt[0][1]), fmaxf(pt[0][2], pt[0][3]));
#pragma unroll
    for (int m = 1; m < 8; ++m)
      mx = fmaxf(mx,
                 fmaxf(fmaxf(pt[m][0], pt[m][1]), fmaxf(pt[m][2], pt[m][3])));
    mx = fmaxf(mx, __shfl_xor(mx, 16));
    mx = fmaxf(mx, __shfl_xor(mx, 32));
    const float m_new = fmaxf(m_run, mx);
    const float fac = fexp2(m_run - m_new);

    float psum = 0.f;
#pragma unroll
    for (int m = 0; m < 8; ++m) {
      float p0 = fexp2(pt[m][0] - m_new);
      float p1 = fexp2(pt[m][1] - m_new);
      float p2 = fexp2(pt[m][2] - m_new);
      float p3 = fexp2(pt[m][3] - m_new);
      psum += (p0 + p1) + (p2 + p3);
      bf16_t pb[4] __attribute__((aligned(8))) = {(bf16_t)p0, (bf16_t)p1,
                                                  (bf16_t)p2, (bf16_t)p3};
      *(uint2*)&p_lds[wid][r][m * 16 + g * 4] = *(const uint2*)pb;
    }
    psum += __shfl_xor(psum, 16);
    psum += __shfl_xor(psum, 32);
    l_run = l_run * fac + psum;
    m_run = m_new;

    // rescale O^T accumulators — fac is lane-local (per l = r)
#pragma unroll
    for (int i = 0; i < 4; ++i) { o0[i] *= fac; o1[i] *= fac; }

    // ---- PV: O^T[d][l] += V2T[d][s] * P^T[s][l]   (8 MFMAs from LDS)
#pragma unroll
    for (int u = 0; u < 4; ++u) {
      bf16x8 pf = *(const bf16x8*)&p_lds[wid][r][u * 32 + g * 8];
      bf16x8 va = *(const bf16x8*)&v_lds[r][u * 32 + g * 8];
      bf16x8 vb = *(const bf16x8*)&v_lds[16 + r][u * 32 + g * 8];
      o0 = mfma16(va, pf, o0);
      o1 = mfma16(vb, pf, o1);
    }
    __syncthreads();  // everyone done with k/v/p before next stage
  }

  // ---- epilogue (per wave): 1/l, V1 gate, store. lane owns l = r.
  const float linv = 1.f / l_run;
  const bf16_t* V1b = V1w + (tokQ + r) * CC + h * DD;
  bf16_t* Mb = MSG + (tokQ + r) * CC + h * DD;
  uint2 v1u0 = *(const uint2*)(V1b + g * 4);
  uint2 v1u1 = *(const uint2*)(V1b + 16 + g * 4);
  const bf16_t* v1a = (const bf16_t*)&v1u0;
  const bf16_t* v1b = (const bf16_t*)&v1u1;
  bf16_t ob0[4] __attribute__((aligned(8)));
  bf16_t ob1[4] __attribute__((aligned(8)));
#pragma unroll
  for (int i = 0; i < 4; ++i) {
    ob0[i] = (bf16_t)(o0[i] * linv * (float)v1a[i]);
    ob1[i] = (bf16_t)(o1[i] * linv * (float)v1b[i]);
  }
  *(uint2*)(Mb + g * 4) = *(const uint2*)ob0;
  *(uint2*)(Mb + 16 + g * 4) = *(const uint2*)ob1;
}

// ---------------------------------------------------------------------------
// Kernel 4: out = MSG @ Wp^T + bp   (f32 output)
// ---------------------------------------------------------------------------
__global__ __launch_bounds__(256) void out_kernel(
    const bf16_t* __restrict__ MSG, const bf16_t* __restrict__ Wp,
    const float* __restrict__ bp, float* __restrict__ out) {
  const int lane = threadIdx.x & 63;
  const int wid = threadIdx.x >> 6;
  const int wm = wid >> 1, wn = wid & 1;
  const int r = lane & 15, g = lane >> 4;
  const int bm = blockIdx.x * 64, bn = blockIdx.y * 64;
  const int row_a0 = bm + wm * 32;
  const int col_b0 = bn + wn * 32;

  f32x4 acc[2][2] = {};
#pragma unroll
  for (int k0 = 0; k0 < CC; k0 += 32) {
    bf16x8 a0 = *(const bf16x8*)(MSG + (size_t)(row_a0 + r) * CC + k0 + g * 8);
    bf16x8 a1 = *(const bf16x8*)(MSG + (size_t)(row_a0 + 16 + r) * CC + k0 + g * 8);
    bf16x8 b0 = *(const bf16x8*)(Wp + (size_t)(col_b0 + r) * CC + k0 + g * 8);
    bf16x8 b1 = *(const bf16x8*)(Wp + (size_t)(col_b0 + 16 + r) * CC + k0 + g * 8);
    acc[0][0] = mfma16(a0, b0, acc[0][0]);
    acc[0][1] = mfma16(a0, b1, acc[0][1]);
    acc[1][0] = mfma16(a1, b0, acc[1][0]);
    acc[1][1] = mfma16(a1, b1, acc[1][1]);
  }
#pragma unroll
  for (int i = 0; i < 2; ++i) {
#pragma unroll
    for (int j = 0; j < 2; ++j) {
      const int row_base = row_a0 + i * 16 + g * 4;
      const int col = col_b0 + j * 16 + r;
      const float bv = bp[col];
#pragma unroll
      for (int t = 0; t < 4; ++t)
        out[(size_t)(row_base + t) * CC + col] = acc[i][j][t] + bv;
    }
  }
}

// ---------------------------------------------------------------------------
extern "C" void kernel_launch(void* const* d_in, const int* in_sizes, int n_in,
                              void* d_out, int out_size, void* d_ws,
                              size_t ws_size, hipStream_t stream) {
  const float* x  = (const float*)d_in[0];
  const float* s1 = (const float*)d_in[1];
  const float* xe = (const float*)d_in[2];
  const float* se = (const float*)d_in[3];
  const float* Wq = (const float*)d_in[4];
  const float* Wk = (const float*)d_in[5];
  const float* Wv = (const float*)d_in[6];
  const float* Wp = (const float*)d_in[7];
  const float* bp = (const float*)d_in[8];
  float* out = (float*)d_out;

  char* ws = (char*)d_ws;
  bf16_t* XQ   = (bf16_t*)(ws);                     // 4 MB  [8192][256]
  bf16_t* SK   = (bf16_t*)(ws + (4u << 20));        // 4 MB
  bf16_t* Wall = (bf16_t*)(ws + (8u << 20));        // 512 KB: Wq,Wk,Wv,Wp bf16
  bf16_t* Qw   = (bf16_t*)(ws + (9u << 20));        // 4 MB (pre-scaled)
  bf16_t* Kw   = (bf16_t*)(ws + (13u << 20));       // 4 MB
  bf16_t* V1w  = (bf16_t*)(ws + (17u << 20));       // 4 MB
  bf16_t* V2T  = (bf16_t*)(ws + (21u << 20));       // 4 MB [n][h][d][s]
  bf16_t* MSG  = (bf16_t*)(ws + (25u << 20));       // 4 MB
  bf16_t* Wpb  = Wall + 3 * CC * CC;

  prep_kernel<<<2048, 256, 0, stream>>>(x, xe, s1, se, Wq, Wk, Wv, Wp, XQ, SK,
                                        Wall);
  proj_kernel<<<dim3(MTOK / 64, CC / 64, 4), 256, 0, stream>>>(
      XQ, SK, Wall, Qw, Kw, V1w, V2T);
  attn_kernel<<<dim3(LL / 64, HH, NB), 256, 0, stream>>>(Qw, Kw, V1w, V2T, MSG);
  out_kernel<<<dim3(MTOK / 64, CC / 64, 1), 256, 0, stream>>>(MSG, Wpb, bp, out);
}

// Round 5
// 70.553 us; speedup vs baseline: 1.7188x; 1.1728x over previous
//
#include <hip/hip_runtime.h>
#include <hip/hip_bf16.h>

// Problem: N=8, L=S=1024, C=256, H=8, D=32
// out = (v1 * softmax_S(q k^T / sqrt(D)) v2) @ Wp^T + bp
// Pipeline: prep (add+bf16) -> 2 merged projections (MFMA GEMM) -> fused attn
// (double-buffered LDS, 128-L tiles) -> out GEMM

typedef __bf16 bf16_t;
using bf16x8 = __attribute__((ext_vector_type(8))) __bf16;
using f32x4  = __attribute__((ext_vector_type(4))) float;

#define NB 8
#define LL 1024
#define SS 1024
#define CC 256
#define HH 8
#define DD 32
#define MTOK (NB * LL)   // 8192 tokens for both L-side and S-side

// 1/sqrt(D) * log2(e): softmax done in exp2 space, folded into Q at proj time
#define QSCALE (0.17677669529663688f * 1.4426950408889634f)

static __device__ __forceinline__ f32x4 mfma16(bf16x8 a, bf16x8 b, f32x4 c) {
  return __builtin_amdgcn_mfma_f32_16x16x32_bf16(a, b, c, 0, 0, 0);
}
static __device__ __forceinline__ float fexp2(float x) {
  return __builtin_amdgcn_exp2f(x);
}

// ---------------------------------------------------------------------------
// Kernel 1: xq = bf16(x + xe), sk = bf16(s1 + se), plus bf16 copies of weights
// ---------------------------------------------------------------------------
__global__ __launch_bounds__(256) void prep_kernel(
    const float* __restrict__ x, const float* __restrict__ xe,
    const float* __restrict__ s1, const float* __restrict__ se,
    const float* __restrict__ wq, const float* __restrict__ wk,
    const float* __restrict__ wv, const float* __restrict__ wp,
    bf16_t* __restrict__ XQ, bf16_t* __restrict__ SK, bf16_t* __restrict__ Wall) {
  const int TOK4 = (MTOK * CC) / 4;  // 524288 float4 per token tensor
  const int W4   = (CC * CC) / 4;    // 16384 float4 per weight matrix
  int i = blockIdx.x * 256 + threadIdx.x;
  const int stride = gridDim.x * 256;
  const int total = 2 * TOK4 + 4 * W4;
  for (; i < total; i += stride) {
    const float4* pa;
    const float4* pb = nullptr;
    bf16_t* o;
    int j;
    if (i < TOK4) {
      pa = (const float4*)x; pb = (const float4*)xe; o = XQ; j = i;
    } else if (i < 2 * TOK4) {
      pa = (const float4*)s1; pb = (const float4*)se; o = SK; j = i - TOK4;
    } else {
      int wi = i - 2 * TOK4;
      int w = wi >> 14;          // / W4
      j = wi & (W4 - 1);
      pa = (const float4*)(w == 0 ? wq : w == 1 ? wk : w == 2 ? wv : wp);
      o = Wall + (size_t)w * CC * CC;
    }
    float4 va = pa[j];
    if (pb) {
      float4 vb = pb[j];
      va.x += vb.x; va.y += vb.y; va.z += vb.z; va.w += vb.w;
    }
    bf16_t t4[4] __attribute__((aligned(8))) = {
        (bf16_t)va.x, (bf16_t)va.y, (bf16_t)va.z, (bf16_t)va.w};
    *(uint2*)(o + 4 * (size_t)j) = *(const uint2*)t4;
  }
}

// ---------------------------------------------------------------------------
// Kernel 2: merged projections (NT GEMM), 2 outputs per A-pass.
// z=0: A=XQ -> Q (pre-scaled by QSCALE) and V1 (both row-major).
// z=1: A=SK -> K (row-major) and V2T (transposed per head [n][h][d][s]).
// A-tile reads amortized over 2 outputs; 8 MFMAs per 6 global loads.
// ---------------------------------------------------------------------------
__global__ __launch_bounds__(256) void proj_kernel(
    const bf16_t* __restrict__ XQ, const bf16_t* __restrict__ SK,
    const bf16_t* __restrict__ Wall,
    bf16_t* __restrict__ Qw, bf16_t* __restrict__ Kw,
    bf16_t* __restrict__ V1w, bf16_t* __restrict__ V2T) {
  const int lane = threadIdx.x & 63;
  const int wid = threadIdx.x >> 6;
  const int wm = wid >> 1, wn = wid & 1;
  const int r = lane & 15, g = lane >> 4;
  const int bm = blockIdx.x * 64, bn = blockIdx.y * 64;
  const int z = blockIdx.z;

  const bf16_t* A  = z ? SK : XQ;
  const bf16_t* W0 = Wall + (size_t)z * CC * CC;  // z=0: Wq, z=1: Wk
  const bf16_t* W1 = Wall + 2 * (size_t)CC * CC;  // Wv

  const int row_a0 = bm + wm * 32;
  const int col_b0 = bn + wn * 32;

  f32x4 acc0[2][2] = {};
  f32x4 acc1[2][2] = {};
#pragma unroll
  for (int k0 = 0; k0 < CC; k0 += 32) {
    bf16x8 a0 = *(const bf16x8*)(A + (size_t)(row_a0 + r) * CC + k0 + g * 8);
    bf16x8 a1 = *(const bf16x8*)(A + (size_t)(row_a0 + 16 + r) * CC + k0 + g * 8);
    bf16x8 b00 = *(const bf16x8*)(W0 + (size_t)(col_b0 + r) * CC + k0 + g * 8);
    bf16x8 b01 = *(const bf16x8*)(W0 + (size_t)(col_b0 + 16 + r) * CC + k0 + g * 8);
    bf16x8 b10 = *(const bf16x8*)(W1 + (size_t)(col_b0 + r) * CC + k0 + g * 8);
    bf16x8 b11 = *(const bf16x8*)(W1 + (size_t)(col_b0 + 16 + r) * CC + k0 + g * 8);
    acc0[0][0] = mfma16(a0, b00, acc0[0][0]);
    acc0[0][1] = mfma16(a0, b01, acc0[0][1]);
    acc0[1][0] = mfma16(a1, b00, acc0[1][0]);
    acc0[1][1] = mfma16(a1, b01, acc0[1][1]);
    acc1[0][0] = mfma16(a0, b10, acc1[0][0]);
    acc1[0][1] = mfma16(a0, b11, acc1[0][1]);
    acc1[1][0] = mfma16(a1, b10, acc1[1][0]);
    acc1[1][1] = mfma16(a1, b11, acc1[1][1]);
  }

#pragma unroll
  for (int i = 0; i < 2; ++i) {
#pragma unroll
    for (int j = 0; j < 2; ++j) {
      const int row_base = row_a0 + i * 16 + g * 4;
      const int col = col_b0 + j * 16 + r;
      if (z == 0) {
#pragma unroll
        for (int t = 0; t < 4; ++t) {
          Qw[(size_t)(row_base + t) * CC + col] =
              (bf16_t)(acc0[i][j][t] * QSCALE);
          V1w[(size_t)(row_base + t) * CC + col] = (bf16_t)acc1[i][j][t];
        }
      } else {
#pragma unroll
        for (int t = 0; t < 4; ++t)
          Kw[(size_t)(row_base + t) * CC + col] = (bf16_t)acc0[i][j][t];
        // transposed per-head store: V2T[((n*H + h)*D + d)][s]
        const int n = row_base >> 10;
        const int s = row_base & (SS - 1);
        const int h = col >> 5;
        const int d = col & (DD - 1);
        bf16_t t4[4] __attribute__((aligned(8)));
#pragma unroll
        for (int t = 0; t < 4; ++t) t4[t] = (bf16_t)acc1[i][j][t];
        *(uint2*)(V2T + ((size_t)((n * HH + h) * DD + d)) * SS + s) =
            *(const uint2*)t4;
      }
    }
  }
}

// ---------------------------------------------------------------------------
// Kernel 3: fused flash attention + v1 gating — double-buffered LDS K/V,
// L-tile 128, 8 waves (512 thr). Grid (L/128, H, N) = 512 blocks = 2/CU.
// 2-phase pipeline per 128-S chunk: issue next chunk's global loads BEFORE
// compute, ds_write after compute, one barrier per chunk (latency hidden
// under 16 MFMAs + softmax).
// Swapped QK^T (rows=S, col=L) and swapped PV (rows=D, col=L): softmax
// stats and rescale factors are lane-local.
// ---------------------------------------------------------------------------
__global__ __launch_bounds__(512) void attn_kernel(
    const bf16_t* __restrict__ Qw, const bf16_t* __restrict__ Kw,
    const bf16_t* __restrict__ V1w, const bf16_t* __restrict__ V2T,
    bf16_t* __restrict__ MSG) {
  __shared__ __align__(16) bf16_t k_lds[2][128][40];   // [buf][s][d+8]  20.0 KB
  __shared__ __align__(16) bf16_t v_lds[2][32][136];   // [buf][d][s+8]  17.0 KB
  __shared__ __align__(16) bf16_t p_lds[8][16][136];   // [w][l][s+8]    34.0 KB

  const int tid = threadIdx.x;
  const int lane = tid & 63;
  const int wid = tid >> 6;  // 0..7
  const int r = lane & 15, g = lane >> 4;
  const int h = blockIdx.y;
  const int n = blockIdx.z;
  const int l0 = blockIdx.x * 128;
  const size_t tokQ = (size_t)n * LL + l0 + wid * 16;  // wave's 16 L-rows

  // Q fragment (B-operand of swapped QK^T); Q is pre-scaled by QSCALE
  const bf16x8 qf = *(const bf16x8*)(Qw + (tokQ + r) * CC + h * DD + g * 8);
  const bf16_t* Kb = Kw + ((size_t)n * SS) * CC + h * DD;
  const bf16_t* Vt = V2T + ((size_t)(n * HH + h)) * DD * SS;

  // staging indices (512 threads): K 128 rows x 4 quads, V 32 rows x 16 quads
  const int ktr = tid >> 2, ktq = tid & 3;
  const int vtr = tid >> 4, vtq = tid & 15;

  float m_run = -1e30f;
  float l_run = 0.f;
  f32x4 o0 = {0.f, 0.f, 0.f, 0.f};  // O^T rows d = g*4+i,    col l = r
  f32x4 o1 = {0.f, 0.f, 0.f, 0.f};  // O^T rows d = 16+g*4+i, col l = r
  const f32x4 zero = {0.f, 0.f, 0.f, 0.f};

  // prologue: stage chunk 0
  uint4 kreg = *(const uint4*)(Kb + (size_t)ktr * CC + ktq * 8);
  uint4 vreg = *(const uint4*)(Vt + (size_t)vtr * SS + vtq * 8);
  *(uint4*)&k_lds[0][ktr][ktq * 8] = kreg;
  *(uint4*)&v_lds[0][vtr][vtq * 8] = vreg;
  __syncthreads();

  for (int c = 0; c < 8; ++c) {
    const int cur = c & 1;
    // ---- issue next chunk's global loads early (latency hides under compute)
    if (c < 7) {
      const int s1 = (c + 1) * 128;
      kreg = *(const uint4*)(Kb + (size_t)(s1 + ktr) * CC + ktq * 8);
      vreg = *(const uint4*)(Vt + (size_t)vtr * SS + s1 + vtq * 8);
    }

    // ---- QK^T: 8 MFMAs from LDS (rows = S, col(lane&15) = L)
    f32x4 pt[8];
#pragma unroll
    for (int m = 0; m < 8; ++m) {
      bf16x8 kf = *(const bf16x8*)&k_lds[cur][m * 16 + r][g * 8];
      pt[m] = mfma16(kf, qf, zero);  // s = c*128 + 16m + 4g + i
    }

    // ---- online softmax (stats per l-column, lane-local after shfl)
    float mx = fmaxf(fmaxf(pt[0][0], pt[0][1]), fmaxf(pt[0][2], pt[0][3]));
#pragma unroll
    for (int m = 1; m < 8; ++m)
      mx = fmaxf(mx,
                 fmaxf(fmaxf(pt[m][0], pt[m][1]), fmaxf(pt[m][2], pt[m][3])));
    mx = fmaxf(mx, __shfl_xor(mx, 16));
    mx = fmaxf(mx, __shfl_xor(mx, 32));
    const float m_new = fmaxf(m_run, mx);
    const float fac = fexp2(m_run - m_new);

    float psum = 0.f;
#pragma unroll
    for (int m = 0; m < 8; ++m) {
      float p0 = fexp2(pt[m][0] - m_new);
      float p1 = fexp2(pt[m][1] - m_new);
      float p2 = fexp2(pt[m][2] - m_new);
      float p3 = fexp2(pt[m][3] - m_new);
      psum += (p0 + p1) + (p2 + p3);
      bf16_t pb[4] __attribute__((aligned(8))) = {(bf16_t)p0, (bf16_t)p1,
                                                  (bf16_t)p2, (bf16_t)p3};
      *(uint2*)&p_lds[wid][r][m * 16 + g * 4] = *(const uint2*)pb;
    }
    psum += __shfl_xor(psum, 16);
    psum += __shfl_xor(psum, 32);
    l_run = l_run * fac + psum;
    m_run = m_new;

    // rescale O^T accumulators — fac is lane-local (per l = r)
#pragma unroll
    for (int i = 0; i < 4; ++i) { o0[i] *= fac; o1[i] *= fac; }

    // ---- PV: O^T[d][l] += V2T[d][s] * P^T[s][l]   (8 MFMAs from LDS)
#pragma unroll
    for (int u = 0; u < 4; ++u) {
      bf16x8 pf = *(const bf16x8*)&p_lds[wid][r][u * 32 + g * 8];
      bf16x8 va = *(const bf16x8*)&v_lds[cur][r][u * 32 + g * 8];
      bf16x8 vb = *(const bf16x8*)&v_lds[cur][16 + r][u * 32 + g * 8];
      o0 = mfma16(va, pf, o0);
      o1 = mfma16(vb, pf, o1);
    }

    // ---- write next chunk into the other buffer (read in c+1 after barrier)
    if (c < 7) {
      *(uint4*)&k_lds[cur ^ 1][ktr][ktq * 8] = kreg;
      *(uint4*)&v_lds[cur ^ 1][vtr][vtq * 8] = vreg;
    }
    __syncthreads();
  }

  // ---- epilogue (per wave): 1/l, V1 gate, store. lane owns l = r.
  const float linv = 1.f / l_run;
  const bf16_t* V1b = V1w + (tokQ + r) * CC + h * DD;
  bf16_t* Mb = MSG + (tokQ + r) * CC + h * DD;
  uint2 v1u0 = *(const uint2*)(V1b + g * 4);
  uint2 v1u1 = *(const uint2*)(V1b + 16 + g * 4);
  const bf16_t* v1a = (const bf16_t*)&v1u0;
  const bf16_t* v1b = (const bf16_t*)&v1u1;
  bf16_t ob0[4] __attribute__((aligned(8)));
  bf16_t ob1[4] __attribute__((aligned(8)));
#pragma unroll
  for (int i = 0; i < 4; ++i) {
    ob0[i] = (bf16_t)(o0[i] * linv * (float)v1a[i]);
    ob1[i] = (bf16_t)(o1[i] * linv * (float)v1b[i]);
  }
  *(uint2*)(Mb + g * 4) = *(const uint2*)ob0;
  *(uint2*)(Mb + 16 + g * 4) = *(const uint2*)ob1;
}

// ---------------------------------------------------------------------------
// Kernel 4: out = MSG @ Wp^T + bp   (f32 output)
// ---------------------------------------------------------------------------
__global__ __launch_bounds__(256) void out_kernel(
    const bf16_t* __restrict__ MSG, const bf16_t* __restrict__ Wp,
    const float* __restrict__ bp, float* __restrict__ out) {
  const int lane = threadIdx.x & 63;
  const int wid = threadIdx.x >> 6;
  const int wm = wid >> 1, wn = wid & 1;
  const int r = lane & 15, g = lane >> 4;
  const int bm = blockIdx.x * 64, bn = blockIdx.y * 64;
  const int row_a0 = bm + wm * 32;
  const int col_b0 = bn + wn * 32;

  f32x4 acc[2][2] = {};
#pragma unroll
  for (int k0 = 0; k0 < CC; k0 += 32) {
    bf16x8 a0 = *(const bf16x8*)(MSG + (size_t)(row_a0 + r) * CC + k0 + g * 8);
    bf16x8 a1 = *(const bf16x8*)(MSG + (size_t)(row_a0 + 16 + r) * CC + k0 + g * 8);
    bf16x8 b0 = *(const bf16x8*)(Wp + (size_t)(col_b0 + r) * CC + k0 + g * 8);
    bf16x8 b1 = *(const bf16x8*)(Wp + (size_t)(col_b0 + 16 + r) * CC + k0 + g * 8);
    acc[0][0] = mfma16(a0, b0, acc[0][0]);
    acc[0][1] = mfma16(a0, b1, acc[0][1]);
    acc[1][0] = mfma16(a1, b0, acc[1][0]);
    acc[1][1] = mfma16(a1, b1, acc[1][1]);
  }
#pragma unroll
  for (int i = 0; i < 2; ++i) {
#pragma unroll
    for (int j = 0; j < 2; ++j) {
      const int row_base = row_a0 + i * 16 + g * 4;
      const int col = col_b0 + j * 16 + r;
      const float bv = bp[col];
#pragma unroll
      for (int t = 0; t < 4; ++t)
        out[(size_t)(row_base + t) * CC + col] = acc[i][j][t] + bv;
    }
  }
}

// ---------------------------------------------------------------------------
extern "C" void kernel_launch(void* const* d_in, const int* in_sizes, int n_in,
                              void* d_out, int out_size, void* d_ws,
                              size_t ws_size, hipStream_t stream) {
  const float* x  = (const float*)d_in[0];
  const float* s1 = (const float*)d_in[1];
  const float* xe = (const float*)d_in[2];
  const float* se = (const float*)d_in[3];
  const float* Wq = (const float*)d_in[4];
  const float* Wk = (const float*)d_in[5];
  const float* Wv = (const float*)d_in[6];
  const float* Wp = (const float*)d_in[7];
  const float* bp = (const float*)d_in[8];
  float* out = (float*)d_out;

  char* ws = (char*)d_ws;
  bf16_t* XQ   = (bf16_t*)(ws);                     // 4 MB  [8192][256]
  bf16_t* SK   = (bf16_t*)(ws + (4u << 20));        // 4 MB
  bf16_t* Wall = (bf16_t*)(ws + (8u << 20));        // 512 KB: Wq,Wk,Wv,Wp bf16
  bf16_t* Qw   = (bf16_t*)(ws + (9u << 20));        // 4 MB (pre-scaled)
  bf16_t* Kw   = (bf16_t*)(ws + (13u << 20));       // 4 MB
  bf16_t* V1w  = (bf16_t*)(ws + (17u << 20));       // 4 MB
  bf16_t* V2T  = (bf16_t*)(ws + (21u << 20));       // 4 MB [n][h][d][s]
  bf16_t* MSG  = (bf16_t*)(ws + (25u << 20));       // 4 MB
  bf16_t* Wpb  = Wall + 3 * CC * CC;

  prep_kernel<<<2048, 256, 0, stream>>>(x, xe, s1, se, Wq, Wk, Wv, Wp, XQ, SK,
                                        Wall);
  proj_kernel<<<dim3(MTOK / 64, CC / 64, 2), 256, 0, stream>>>(
      XQ, SK, Wall, Qw, Kw, V1w, V2T);
  attn_kernel<<<dim3(LL / 128, HH, NB), 512, 0, stream>>>(Qw, Kw, V1w, V2T,
                                                          MSG);
  out_kernel<<<dim3(MTOK / 64, CC / 64, 1), 256, 0, stream>>>(MSG, Wpb, bp, out);
}